// Round 12
// baseline (42.807 us; speedup 1.0000x reference)
//
#include <hip/hip_runtime.h>
#include <math.h>

#define B_TOTAL 16384
#define NQ 512
#define NUM 3

typedef unsigned long long u64;

// One wave per batch, 4 waves/block, no LDS.
// Exact top-8 by merge-sort reduction (chain depth = ONE butterfly):
//   - pack conf as u64 (monotone(conf)<<32 | 511-n): distinct keys, u64
//     descending == conf descending with smaller-index-first (exact ties).
//   - lane-local Batcher sort of 8 (19 cswaps, no cross-lane).
//   - 6 xor-butterfly rounds: exchange sorted-8, keep top-8 of the union
//     (Batcher half-clean max(a[i],b[7-i]) -> bitonic valley -> 12-cswap
//     bitonic re-sort). All lanes converge to the global sorted top-8.
// Then greedy #2/#3 resolved by two ballots over ranks 0..7 (~97% of
// batches); rare exact fallback continues the scan from rank 8 with
// consume-and-repeat argmax (R11-validated, absmax 0 with it exercised).
__global__ __launch_bounds__(256) void greedy_nms_kernel(
    const float* __restrict__ conf,   // [B, NQ]
    const float* __restrict__ pos,    // [B, NQ, 3]
    float* __restrict__ out)          // [B, NUM, 3]
{
    const int lane = threadIdx.x & 63;
    const int b = (blockIdx.x << 2) | (threadIdx.x >> 6);   // grid*4 == B

    const float* cb = conf + (size_t)b * NQ;
    const float* pb = pos  + (size_t)b * NQ * 3;

    // conf: lane owns elements 8l..8l+7 (two 1KB-coalesced float4 loads)
    const float4* cb4 = reinterpret_cast<const float4*>(cb);
    float4 c0 = cb4[lane * 2 + 0];
    float4 c1 = cb4[lane * 2 + 1];

    // packed u64 keys
    u64 s[8];
    {
        float f[8] = {c0.x, c0.y, c0.z, c0.w, c1.x, c1.y, c1.z, c1.w};
        #pragma unroll
        for (int i = 0; i < 8; ++i) {
            int bi = __float_as_int(f[i]);
            unsigned u = (unsigned)bi ^ ((unsigned)(bi >> 31) | 0x80000000u);
            s[i] = ((u64)u << 32) | (unsigned)(NQ - 1 - ((lane << 3) + i));
        }
    }

    #define CSW(a, c) { if ((c) > (a)) { u64 t_ = (a); (a) = (c); (c) = t_; } }

    // lane-local descending sort (Batcher odd-even mergesort, 19 comparators)
    CSW(s[0],s[1]) CSW(s[2],s[3]) CSW(s[4],s[5]) CSW(s[6],s[7])
    CSW(s[0],s[2]) CSW(s[1],s[3]) CSW(s[4],s[6]) CSW(s[5],s[7])
    CSW(s[1],s[2]) CSW(s[5],s[6])
    CSW(s[0],s[4]) CSW(s[1],s[5]) CSW(s[2],s[6]) CSW(s[3],s[7])
    CSW(s[2],s[4]) CSW(s[3],s[5])
    CSW(s[1],s[2]) CSW(s[3],s[4]) CSW(s[5],s[6])

    // 6 butterfly merge rounds; afterwards every lane holds the global
    // sorted (descending) top-8 packed keys.
    #pragma unroll
    for (int off = 1; off < 64; off <<= 1) {
        u64 o[8];
        #pragma unroll
        for (int i = 0; i < 8; ++i) o[i] = __shfl_xor(s[i], off);
        u64 m[8];
        #pragma unroll
        for (int i = 0; i < 8; ++i) {
            u64 x = o[7 - i];
            m[i] = s[i] > x ? s[i] : x;   // half-clean: top-8 multiset, bitonic
        }
        // bitonic (valley) -> descending: distances 4, 2, 1
        CSW(m[0],m[4]) CSW(m[1],m[5]) CSW(m[2],m[6]) CSW(m[3],m[7])
        CSW(m[0],m[2]) CSW(m[1],m[3]) CSW(m[4],m[6]) CSW(m[5],m[7])
        CSW(m[0],m[1]) CSW(m[2],m[3]) CSW(m[4],m[5]) CSW(m[6],m[7])
        #pragma unroll
        for (int i = 0; i < 8; ++i) s[i] = m[i];
    }

    // lane i<8 gathers the rank-i pos row (lanes >=8 read rank-0's line,
    // which coalesces to a single broadcast request)
    int myn = NQ - 1 - (int)(s[0] & 0x1ffu);
    #pragma unroll
    for (int i = 1; i < 8; ++i)
        if (lane == i) myn = NQ - 1 - (int)(s[i] & 0x1ffu);
    float cx = pb[myn * 3 + 0];
    float cy = pb[myn * 3 + 1];
    float cz = pb[myn * 3 + 2];

    const float TH  = 0.78539816339744830961f; // pi/4 (f32 == jnp thresh)
    const float CLO = 0.70710478f;             // cos(pi/4) - ~2e-6
    const float CHI = 0.70710878f;             // cos(pi/4) + ~2e-6

    auto passv = [&](float ax, float ay, float az,
                     float px, float py, float pz) -> bool {
        float d = fabsf(ax * px + ay * py + az * pz);
        if (d <= CLO) return true;                  // clearly >= pi/4
        if (d >= CHI) return false;                 // clearly <  pi/4
        return acosf(fminf(d, 1.f)) >= TH;          // exact at boundary
    };

    // greedy over ranks 0..7 via ballots
    const float p1x = __shfl(cx, 0), p1y = __shfl(cy, 0), p1z = __shfl(cz, 0);
    u64 ball1 = __ballot(passv(p1x, p1y, p1z, cx, cy, cz)) & 0xFEull;

    float o2x, o2y, o2z;
    const bool found2 = (ball1 != 0);
    if (found2) {
        const int i2 = __ffsll(ball1) - 1;
        o2x = __shfl(cx, i2); o2y = __shfl(cy, i2); o2z = __shfl(cz, i2);
        u64 ball3 = ball1 & __ballot(passv(o2x, o2y, o2z, cx, cy, cz))
                          & ~((2ull << i2) - 1);
        if (ball3 != 0) {                           // fast path: ~97%
            const int i3 = __ffsll(ball3) - 1;
            const float o3x = __shfl(cx, i3);
            const float o3y = __shfl(cy, i3);
            const float o3z = __shfl(cz, i3);
            if (lane == 0) {
                float* ob = out + (size_t)b * 9;
                ob[0] = p1x; ob[1] = p1y; ob[2] = p1z;
                ob[3] = o2x; ob[4] = o2y; ob[5] = o2z;
                ob[6] = o3x; ob[7] = o3y; ob[8] = o3z;
            }
            return;
        }
    }

    // ---- rare exact fallback: continue greedy scan from rank 8 ----
    const float p0x = pb[0], p0y = pb[1], p0z = pb[2];   // reference default

    // rebuild u32 keys and consume ranks 0..7 (known to all lanes via s[])
    unsigned k[8];
    {
        float f[8] = {c0.x, c0.y, c0.z, c0.w, c1.x, c1.y, c1.z, c1.w};
        #pragma unroll
        for (int i = 0; i < 8; ++i) {
            int bi = __float_as_int(f[i]);
            k[i] = (unsigned)bi ^ ((unsigned)(bi >> 31) | 0x80000000u);
        }
    }
    #pragma unroll
    for (int r = 0; r < 8; ++r) {
        const int nr = NQ - 1 - (int)(s[r] & 0x1ffu);
        const int osl = ((nr >> 3) == lane) ? (nr & 7) : 8;
        #pragma unroll
        for (int q = 0; q < 8; ++q)
            if (osl == q) k[q] = 0u;
    }

    // accepted-set state; zero vector auto-passes (mirrors masked-inf ref)
    float a1x = 0.f, a1y = 0.f, a1z = 0.f;
    float o3x = p0x, o3y = p0y, o3z = p0z;
    int count;
    if (found2) { a1x = o2x; a1y = o2y; a1z = o2z; count = 2; }
    else        { o2x = p0x; o2y = p0y; o2z = p0z; count = 1; }

    #pragma unroll 1
    for (int it = 8; it < NQ; ++it) {
        // consume-and-repeat argmax (R11-validated)
        bool s01 = k[1] > k[0];
        unsigned m01 = s01 ? k[1] : k[0]; int i01 = s01 ? 1 : 0;
        bool s23 = k[3] > k[2];
        unsigned m23 = s23 ? k[3] : k[2]; int i23 = s23 ? 3 : 2;
        bool s45 = k[5] > k[4];
        unsigned m45 = s45 ? k[5] : k[4]; int i45 = s45 ? 5 : 4;
        bool s67 = k[7] > k[6];
        unsigned m67 = s67 ? k[7] : k[6]; int i67 = s67 ? 7 : 6;
        if (m23 > m01) { m01 = m23; i01 = i23; }
        if (m67 > m45) { m45 = m67; i45 = i67; }
        if (m45 > m01) { m01 = m45; i01 = i45; }
        u64 K = ((u64)m01 << 32) |
                (unsigned)(NQ - 1 - ((lane << 3) + i01));
        #pragma unroll
        for (int off = 1; off < 64; off <<= 1) {
            u64 o = __shfl_xor(K, off);
            if (o > K) K = o;
        }
        if ((unsigned)(K >> 32) == 0u) break;       // keys exhausted
        const int n = NQ - 1 - (int)(K & 0x1ffu);
        {
            const int osl = ((n >> 3) == lane) ? (n & 7) : 8;
            #pragma unroll
            for (int q = 0; q < 8; ++q)
                if (osl == q) k[q] = 0u;
        }
        const float px = pb[n * 3 + 0];             // wave-uniform row load
        const float py = pb[n * 3 + 1];
        const float pz = pb[n * 3 + 2];
        bool add = passv(p1x, p1y, p1z, px, py, pz) &&
                   passv(a1x, a1y, a1z, px, py, pz);
        if (add) {
            if (count == 1) {
                o2x = px; o2y = py; o2z = pz;
                a1x = px; a1y = py; a1z = pz;
                count = 2;
            } else {
                o3x = px; o3y = py; o3z = pz;
                break;
            }
        }
    }

    if (lane == 0) {
        float* ob = out + (size_t)b * 9;
        ob[0] = p1x; ob[1] = p1y; ob[2] = p1z;
        ob[3] = o2x; ob[4] = o2y; ob[5] = o2z;
        ob[6] = o3x; ob[7] = o3y; ob[8] = o3z;
    }
}

extern "C" void kernel_launch(void* const* d_in, const int* in_sizes, int n_in,
                              void* d_out, int out_size, void* d_ws, size_t ws_size,
                              hipStream_t stream) {
    const float* pred_logits = (const float*)d_in[0]; // [B, NQ, 1]
    const float* pred_pos    = (const float*)d_in[1]; // [B, NQ, 3]
    float* out = (float*)d_out;                       // [B, NUM, 3]

    const int grid = B_TOTAL / 4;                     // 4 waves/block
    greedy_nms_kernel<<<grid, 256, 0, stream>>>(pred_logits, pred_pos, out);
}

// Round 13
// 26.399 us; speedup vs baseline: 1.6216x; 1.6216x over previous
//
#include <hip/hip_runtime.h>
#include <math.h>

#define B_TOTAL 16384
#define NQ 512
#define NUM 3

// One wave per batch, 4 waves/block. R6/R10's masked-argmax algorithm
// (#1 = argmax conf; #2 = argmax among passers vs p1; #3 = passers vs p1&p2)
// with ALL cross-lane reductions done via DPP row ops (pure VALU, ~2-4 cy
// per step) instead of ds_bpermute shuffles (~35 cy, LDS pipe). The kernel
// contains zero ds_bpermute:
//   - argmax = DPP umax-reduce of keys -> readlane(63), then exact stable
//     tie-break via DPP umin-reduce of (first-equal-slot -> n = im*64+lane).
//   - winner n is wave-uniform (SGPR) -> get_row is a broadcast LDS read.
// Data path identical to R10: pos staged column-major to LDS (coalesced 1KB
// float4 bursts), element n = i*64+lane, conflict-free mask_keys reads.
typedef unsigned u32;

__device__ __forceinline__ u32 wave_umax_dpp(u32 v) {
    u32 r = v, t;
    t = (u32)__builtin_amdgcn_update_dpp(0, (int)r, 0x111, 0xF, 0xF, false);
    r = t > r ? t : r;   // row_shr:1
    t = (u32)__builtin_amdgcn_update_dpp(0, (int)r, 0x112, 0xF, 0xF, false);
    r = t > r ? t : r;   // row_shr:2
    t = (u32)__builtin_amdgcn_update_dpp(0, (int)r, 0x114, 0xF, 0xF, false);
    r = t > r ? t : r;   // row_shr:4
    t = (u32)__builtin_amdgcn_update_dpp(0, (int)r, 0x118, 0xF, 0xF, false);
    r = t > r ? t : r;   // row_shr:8
    t = (u32)__builtin_amdgcn_update_dpp(0, (int)r, 0x142, 0xF, 0xF, false);
    r = t > r ? t : r;   // row_bcast:15
    t = (u32)__builtin_amdgcn_update_dpp(0, (int)r, 0x143, 0xF, 0xF, false);
    r = t > r ? t : r;   // row_bcast:31
    return (u32)__builtin_amdgcn_readlane((int)r, 63);  // wave-uniform
}

__device__ __forceinline__ u32 wave_umin_dpp(u32 v) {
    u32 r = v, t;
    t = (u32)__builtin_amdgcn_update_dpp(-1, (int)r, 0x111, 0xF, 0xF, false);
    r = t < r ? t : r;
    t = (u32)__builtin_amdgcn_update_dpp(-1, (int)r, 0x112, 0xF, 0xF, false);
    r = t < r ? t : r;
    t = (u32)__builtin_amdgcn_update_dpp(-1, (int)r, 0x114, 0xF, 0xF, false);
    r = t < r ? t : r;
    t = (u32)__builtin_amdgcn_update_dpp(-1, (int)r, 0x118, 0xF, 0xF, false);
    r = t < r ? t : r;
    t = (u32)__builtin_amdgcn_update_dpp(-1, (int)r, 0x142, 0xF, 0xF, false);
    r = t < r ? t : r;
    t = (u32)__builtin_amdgcn_update_dpp(-1, (int)r, 0x143, 0xF, 0xF, false);
    r = t < r ? t : r;
    return (u32)__builtin_amdgcn_readlane((int)r, 63);  // wave-uniform
}

__global__ __launch_bounds__(256) void greedy_nms_kernel(
    const float* __restrict__ conf,   // [B, NQ]
    const float* __restrict__ pos,    // [B, NQ, 3]
    float* __restrict__ out)          // [B, NUM, 3]
{
    __shared__ float lds[4 * NQ * 3];            // 24 KB: 6 KB per wave
    const int lane = threadIdx.x & 63;
    const int wv   = threadIdx.x >> 6;
    const int b    = (blockIdx.x << 2) | wv;     // grid*4 == B_TOTAL

    const float* cb = conf + (size_t)b * NQ;
    const float* pb = pos  + (size_t)b * NQ * 3;
    float* wl = lds + wv * (NQ * 3);

    // ---- pos: column-major float4 loads (fully coalesced), stage to LDS ----
    const float4* pb4 = reinterpret_cast<const float4*>(pb);
    float4 t0 = pb4[0 * 64 + lane];
    float4 t1 = pb4[1 * 64 + lane];
    float4 t2 = pb4[2 * 64 + lane];
    float4 t3 = pb4[3 * 64 + lane];
    float4 t4 = pb4[4 * 64 + lane];
    float4 t5 = pb4[5 * 64 + lane];

    // ---- conf: column-major dwords; slot i <-> element n = i*64+lane ----
    float c[8];
    #pragma unroll
    for (int i = 0; i < 8; ++i) c[i] = cb[i * 64 + lane];

    float4* wl4 = reinterpret_cast<float4*>(wl);
    wl4[0 * 64 + lane] = t0;
    wl4[1 * 64 + lane] = t1;
    wl4[2 * 64 + lane] = t2;
    wl4[3 * 64 + lane] = t3;
    wl4[4 * 64 + lane] = t4;
    wl4[5 * 64 + lane] = t5;

    // monotone float->u32 keys; key 0 == consumed/failed (no NaN/-inf input)
    u32 k[8];
    #pragma unroll
    for (int i = 0; i < 8; ++i) {
        int bi = __float_as_int(c[i]);
        k[i] = (u32)bi ^ ((u32)(bi >> 31) | 0x80000000u);
    }

    __syncthreads();

    // exact argmax via two DPP reduces; returns wave-uniform element index n
    // and the max key (0 => keys exhausted). Tie-break: min n == reference's
    // stable smaller-index rule (column-major map is order-preserving per
    // lane; min over n handles cross-lane exactly).
    auto argmax_dpp = [&](u32& gm_out) -> int {
        u32 m = k[0];
        #pragma unroll
        for (int i = 1; i < 8; ++i) m = k[i] > m ? k[i] : m;
        const u32 gm = wave_umax_dpp(m);
        int im = 8;
        #pragma unroll
        for (int i = 7; i >= 0; --i)
            if (k[i] == gm) im = i;                 // first equal slot
        const u32 candn = (im < 8) ? (u32)((im << 6) | lane) : 0xFFFFFFFFu;
        const u32 n = wave_umin_dpp(candn);
        gm_out = gm;
        return (int)n;
    };

    auto consume = [&](int n) {
        const int ci = ((n & 63) == lane) ? (n >> 6) : 8;
        #pragma unroll
        for (int i = 0; i < 8; ++i)
            if (ci == i) k[i] = 0u;
    };

    // wave-uniform n -> broadcast LDS read (same addr: conflict-free)
    auto get_row = [&](int n, float& x, float& y, float& z) {
        x = wl[3 * n + 0]; y = wl[3 * n + 1]; z = wl[3 * n + 2];
    };

    const float TH  = 0.78539816339744830961f; // pi/4 (f32 == jnp thresh)
    const float CLO = 0.70710478f;             // cos(pi/4) - ~2e-6
    const float CHI = 0.70710878f;             // cos(pi/4) + ~2e-6

    // zero keys of items failing the angle test vs (px,py,pz); reads are
    // conflict-free: dword index 192i+3*lane -> bank 3*lane mod 32.
    auto mask_keys = [&](float px, float py, float pz) {
        #pragma unroll
        for (int i = 0; i < 8; ++i) {
            const int o = 3 * (i * 64 + lane);
            float x = wl[o + 0], y = wl[o + 1], z = wl[o + 2];
            float d = fabsf(x * px + y * py + z * pz);
            bool pass;
            if (d <= CLO)      pass = true;   // clearly >= pi/4
            else if (d >= CHI) pass = false;  // clearly <  pi/4
            else               pass = (acosf(fminf(d, 1.f)) >= TH); // exact
            if (!pass) k[i] = 0u;
        }
    };

    // ---- #1: global argmax ----
    u32 gm1;
    const int w1 = argmax_dpp(gm1);
    float p1x, p1y, p1z;
    get_row(w1, p1x, p1y, p1z);
    consume(w1);

    // ---- #2: argmax among items passing vs p1 ----
    mask_keys(p1x, p1y, p1z);
    u32 gm2;
    const int w2 = argmax_dpp(gm2);

    float o2x, o2y, o2z, o3x, o3y, o3z;
    if (gm2 != 0u) {                           // wave-uniform
        get_row(w2, o2x, o2y, o2z);
        // ---- #3: additionally pass vs p2 (w2 self-fails: |dot|=1) ----
        mask_keys(o2x, o2y, o2z);
        u32 gm3;
        const int w3 = argmax_dpp(gm3);
        if (gm3 != 0u) {
            get_row(w3, o3x, o3y, o3z);
        } else {
            get_row(0, o3x, o3y, o3z);         // fallback = pos[0]
        }
    } else {
        get_row(0, o2x, o2y, o2z);             // fallback = pos[0]
        o3x = o2x; o3y = o2y; o3z = o2z;
    }

    if (lane == 0) {
        float* ob = out + (size_t)b * 9;
        ob[0] = p1x; ob[1] = p1y; ob[2] = p1z;
        ob[3] = o2x; ob[4] = o2y; ob[5] = o2z;
        ob[6] = o3x; ob[7] = o3y; ob[8] = o3z;
    }
}

extern "C" void kernel_launch(void* const* d_in, const int* in_sizes, int n_in,
                              void* d_out, int out_size, void* d_ws, size_t ws_size,
                              hipStream_t stream) {
    const float* pred_logits = (const float*)d_in[0]; // [B, NQ, 1]
    const float* pred_pos    = (const float*)d_in[1]; // [B, NQ, 3]
    float* out = (float*)d_out;                       // [B, NUM, 3]

    const int grid = B_TOTAL / 4;                     // 4 waves/block
    greedy_nms_kernel<<<grid, 256, 0, stream>>>(pred_logits, pred_pos, out);
}